// Round 10
// baseline (70.392 us; speedup 1.0000x reference)
//
#include <hip/hip_runtime.h>

#define NN 2048
#define EE 65536
#define HIDD 12
#define NH 4
#define TEDD 16
#define NCLSS 4
#define H48 48
#define SLOT 128   // fixed edge-slots per dst (max degree ~55 << 128)

__device__ __forceinline__ float read_t(const int* p){
  int i = *p;
  if (i >= 0 && i < 100000) return (float)i;   // int-encoded scalar (expected)
  return __int_as_float(i);                     // defensive: float-encoded scalar
}

// layer-1 output h1[12] from (class cd, neighbor-class counts nf0..3), via the
// 4-row class tables. Exact same math as the per-node reference evaluation.
__device__ __forceinline__ void l1h(int cd, float nf0, float nf1, float nf2, float nf3,
    const float* SL, const float* vL, const float* skL, float r[HIDD])
{
  #pragma unroll
  for (int d=0; d<HIDD; d++) r[d] = 0.f;
  #pragma unroll
  for (int h=0; h<NH; h++){
    float s0 = SL[cd*16 + h*4 + 0];
    float s1 = SL[cd*16 + h*4 + 1];
    float s2 = SL[cd*16 + h*4 + 2];
    float s3 = SL[cd*16 + h*4 + 3];
    float m = -INFINITY;
    if (nf0 > 0.f) m = fmaxf(m, s0);
    if (nf1 > 0.f) m = fmaxf(m, s1);
    if (nf2 > 0.f) m = fmaxf(m, s2);
    if (nf3 > 0.f) m = fmaxf(m, s3);
    float w0 = (nf0 > 0.f) ? nf0*__expf(s0 - m) : 0.f;
    float w1 = (nf1 > 0.f) ? nf1*__expf(s1 - m) : 0.f;
    float w2 = (nf2 > 0.f) ? nf2*__expf(s2 - m) : 0.f;
    float w3 = (nf3 > 0.f) ? nf3*__expf(s3 - m) : 0.f;
    float inv = 1.0f / (w0 + w1 + w2 + w3 + 1e-16f);
    #pragma unroll
    for (int d=0; d<HIDD; d++){
      float num = w0*vL[0*H48 + h*HIDD + d] + w1*vL[1*H48 + h*HIDD + d]
                + w2*vL[2*H48 + h*HIDD + d] + w3*vL[3*H48 + h*HIDD + d];
      r[d] = fmaf(num, inv, r[d]);
    }
  }
  #pragma unroll
  for (int d=0; d<HIDD; d++)
    r[d] = fmaxf(fmaf(r[d], 0.25f, skL[cd*HIDD + d]), 0.f);
}

// ==== k_init: block 0 = layer-1 class tables + 4x4x4 score table;
//              blocks 1-4 = zero cnt+ncnt (10240 ints) + class extraction =====
__global__ __launch_bounds__(512) void k_init(
    const float* __restrict__ x, const int* __restrict__ t,
    const float* __restrict__ tW, const float* __restrict__ tb,
    const float* __restrict__ Wq, const float* __restrict__ bq,
    const float* __restrict__ Wk, const float* __restrict__ bk,
    const float* __restrict__ Wv, const float* __restrict__ bv,
    const float* __restrict__ Ws, const float* __restrict__ bs,
    float* __restrict__ v1t, float* __restrict__ sk1t, float* __restrict__ Stab,
    int* __restrict__ cls, int* __restrict__ zr)
{
  const int tid = threadIdx.x;
  if (blockIdx.x > 0){
    int g = (blockIdx.x - 1)*512 + tid;               // 0..2047
    #pragma unroll
    for (int i=g; i<NN*(1+NCLSS); i+=2048) zr[i] = 0; // cnt + ncnt
    const float* xr = x + g*NCLSS;
    int c = (xr[1]>0.5f) ? 1 : ((xr[2]>0.5f) ? 2 : ((xr[3]>0.5f) ? 3 : 0));
    cls[g] = c;
    return;
  }

  __shared__ float teL[TEDD];
  __shared__ float q1tL[NCLSS][H48];
  __shared__ float k1tL[NCLSS][H48];
  if (tid < TEDD){
    float tf = read_t(t) / 100.0f;
    float lsc = __logf(10000.0f) / 7.0f;
    float emb[TEDD];
    #pragma unroll
    for (int i=0;i<8;i++){
      float vv = tf * __expf(-(float)i * lsc);
      emb[i] = __sinf(vv); emb[i+8] = __cosf(vv);
    }
    float acc = tb[tid];
    #pragma unroll
    for (int kk=0;kk<TEDD;kk++) acc = fmaf(emb[kk], tW[kk*TEDD+tid], acc);
    teL[tid] = acc;
  }
  __syncthreads();

  if (tid < NCLSS*H48){
    int c = tid / H48, j = tid - c*H48;
    // one-hot fma adds of 0.0 are exact no-ops -> identical to per-node qkv1
    float aq = bq[j] + Wq[c*H48+j];
    float ak = bk[j] + Wk[c*H48+j];
    float av = bv[j] + Wv[c*H48+j];
    #pragma unroll
    for (int d=0; d<TEDD; d++){
      float te = teL[d];
      aq = fmaf(te, Wq[(NCLSS+d)*H48+j], aq);
      ak = fmaf(te, Wk[(NCLSS+d)*H48+j], ak);
      av = fmaf(te, Wv[(NCLSS+d)*H48+j], av);
    }
    q1tL[c][j] = aq; k1tL[c][j] = ak; v1t[c*H48+j] = av;
  } else if (tid < NCLSS*H48 + NCLSS*HIDD){
    int u = tid - NCLSS*H48;
    int c = u / HIDD, j = u - c*HIDD;
    float as = bs[j] + Ws[c*HIDD+j];
    #pragma unroll
    for (int d=0; d<TEDD; d++) as = fmaf(teL[d], Ws[(NCLSS+d)*HIDD+j], as);
    sk1t[c*HIDD+j] = as;
  }
  __syncthreads();

  if (tid < 64){
    int cd = tid >> 4, h = (tid >> 2) & 3, c = tid & 3;
    float s = 0.f;
    #pragma unroll
    for (int d=0; d<HIDD; d++) s = fmaf(q1tL[cd][h*HIDD+d], k1tL[c][h*HIDD+d], s);
    Stab[tid] = s * 0.28867513459481287f;   // 1/sqrt(12)
  }
}

// ==== k_fill: edge-table scatter + per-dst class histogram ===================
__global__ __launch_bounds__(512) void k_fill(
    const int* __restrict__ ei, const int* __restrict__ cls,
    int* __restrict__ cnt, int* __restrict__ ncnt, int* __restrict__ slot)
{
  int e = blockIdx.x*512 + threadIdx.x;
  int s = ei[e], d = ei[EE + e];
  int pos = atomicAdd(&cnt[d], 1);
  if (pos < SLOT) slot[d*SLOT + pos] = s;
  atomicAdd(&ncnt[d*NCLSS + cls[s]], 1);
}

// ==== k_mega: full layer-2 per wave with neighbor h recomputed from tables ===
__global__ __launch_bounds__(512) void k_mega(
    const int* __restrict__ cls, const int* __restrict__ cnt,
    const int* __restrict__ ncnt, const int* __restrict__ slot,
    const float* __restrict__ v1t, const float* __restrict__ sk1t,
    const float* __restrict__ Stab,
    const float* __restrict__ Wq2, const float* __restrict__ bq2,
    const float* __restrict__ Wk2, const float* __restrict__ bk2,
    const float* __restrict__ Wv2, const float* __restrict__ bv2,
    const float* __restrict__ Ws2, const float* __restrict__ bs2,
    const float* __restrict__ Wn, const float* __restrict__ bn,
    const float* __restrict__ We1, const float* __restrict__ be1,
    float* __restrict__ A, float* __restrict__ B, float* __restrict__ outNL)
{
  const int tid  = threadIdx.x;
  const int wave = tid >> 6;
  const int lane = tid & 63;
  const int node = blockIdx.x*8 + wave;

  __shared__ float SL[64], vL[NCLSS*H48], skL[NCLSS*HIDD];
  __shared__ float qsw[8][H48], uw[8][H48], c0w[8][NH], skw[8][HIDD], yw[8][H48];
  if (tid < 64) SL[tid] = Stab[tid];
  else if (tid < 64 + NCLSS*H48) vL[tid-64] = v1t[tid-64];
  else if (tid < 64 + NCLSS*H48 + NCLSS*HIDD) skL[tid-64-NCLSS*H48] = sk1t[tid-64-NCLSS*H48];
  __syncthreads();

  // own node: layer-1 h from tables (all lanes, redundant)
  int cd = cls[node];
  const int4 nc = *(const int4*)(ncnt + node*NCLSS);
  float r1[HIDD];
  l1h(cd, (float)nc.x, (float)nc.y, (float)nc.z, (float)nc.w, SL, vL, skL, r1);

  // q2 row and skip2 for this node -> LDS
  if (lane < H48){
    float aq = bq2[lane];
    #pragma unroll
    for (int d=0; d<HIDD; d++) aq = fmaf(r1[d], Wq2[d*H48+lane], aq);
    qsw[wave][lane] = aq;
  } else if (lane < H48+HIDD){
    int j = lane - H48;
    float as = bs2[j];
    #pragma unroll
    for (int d=0; d<HIDD; d++) as = fmaf(r1[d], Ws2[d*HIDD+j], as);
    skw[wave][j] = as;
  }
  __syncthreads();

  // u_h[d] = sum_j Wk2[d][h*12+j] * q2[h*12+j]; c0_h = q2_h . bk2_h
  if (lane < H48){
    int h = lane / HIDD, dd = lane - h*HIDD;
    float u = 0.f;
    #pragma unroll
    for (int jj=0; jj<HIDD; jj++)
      u = fmaf(Wk2[dd*H48 + h*HIDD + jj], qsw[wave][h*HIDD+jj], u);
    uw[wave][lane] = u;
  } else if (lane < H48+NH){
    int h = lane - H48;
    float c0 = 0.f;
    #pragma unroll
    for (int jj=0; jj<HIDD; jj++)
      c0 = fmaf(qsw[wave][h*HIDD+jj], bk2[h*HIDD+jj], c0);
    c0w[wave][h] = c0;
  }
  __syncthreads();

  // neighbor sweep: one src per lane, online softmax over <=2 chunks
  const float ksc = 0.28867513459481287f;
  float m0=-INFINITY, m1=-INFINITY, m2=-INFINITY, m3=-INFINITY;
  float s0=0.f, s1=0.f, s2=0.f, s3=0.f;
  float ha0[HIDD], ha1[HIDD], ha2[HIDD], ha3[HIDD];
  #pragma unroll
  for (int d=0; d<HIDD; d++){ ha0[d]=0.f; ha1[d]=0.f; ha2[d]=0.f; ha3[d]=0.f; }

  int dg = cnt[node]; dg = (dg > SLOT) ? SLOT : dg;
  for (int base=0; base<dg; base+=64){
    int i = base + lane;
    bool val = i < dg;
    int src = val ? slot[node*SLOT + i] : 0;
    int cs = cls[src];
    const int4 snc = *(const int4*)(ncnt + src*NCLSS);
    float hs[HIDD];
    l1h(cs, (float)snc.x, (float)snc.y, (float)snc.z, (float)snc.w, SL, vL, skL, hs);

    float sc0 = c0w[wave][0], sc1 = c0w[wave][1], sc2 = c0w[wave][2], sc3 = c0w[wave][3];
    #pragma unroll
    for (int dd=0; dd<HIDD; dd++){
      float hd = hs[dd];
      sc0 = fmaf(uw[wave][0*HIDD+dd], hd, sc0);
      sc1 = fmaf(uw[wave][1*HIDD+dd], hd, sc1);
      sc2 = fmaf(uw[wave][2*HIDD+dd], hd, sc2);
      sc3 = fmaf(uw[wave][3*HIDD+dd], hd, sc3);
    }
    sc0 *= ksc; sc1 *= ksc; sc2 *= ksc; sc3 *= ksc;
    if (!val){ sc0 = -INFINITY; sc1 = -INFINITY; sc2 = -INFINITY; sc3 = -INFINITY; }

    float c0m=sc0, c1m=sc1, c2m=sc2, c3m=sc3;
    #pragma unroll
    for (int st=1; st<64; st<<=1){
      c0m = fmaxf(c0m, __shfl_xor(c0m, st, 64));
      c1m = fmaxf(c1m, __shfl_xor(c1m, st, 64));
      c2m = fmaxf(c2m, __shfl_xor(c2m, st, 64));
      c3m = fmaxf(c3m, __shfl_xor(c3m, st, 64));
    }
    // online rescale (first chunk: exp(-inf - finite)=0 zeroes the empty accums)
    float n0=fmaxf(m0,c0m), n1=fmaxf(m1,c1m), n2=fmaxf(m2,c2m), n3=fmaxf(m3,c3m);
    float f0=__expf(m0-n0), f1=__expf(m1-n1), f2=__expf(m2-n2), f3=__expf(m3-n3);
    s0*=f0; s1*=f1; s2*=f2; s3*=f3;
    #pragma unroll
    for (int d=0; d<HIDD; d++){ ha0[d]*=f0; ha1[d]*=f1; ha2[d]*=f2; ha3[d]*=f3; }
    m0=n0; m1=n1; m2=n2; m3=n3;

    float w0=__expf(sc0-m0), w1=__expf(sc1-m1), w2=__expf(sc2-m2), w3=__expf(sc3-m3);
    s0+=w0; s1+=w1; s2+=w2; s3+=w3;
    #pragma unroll
    for (int d=0; d<HIDD; d++){
      float hd = hs[d];
      ha0[d] = fmaf(w0, hd, ha0[d]);
      ha1[d] = fmaf(w1, hd, ha1[d]);
      ha2[d] = fmaf(w2, hd, ha2[d]);
      ha3[d] = fmaf(w3, hd, ha3[d]);
    }
  }

  // cross-lane reduction of s_h and ha_h (butterfly -> all lanes hold sums)
  #pragma unroll
  for (int st=1; st<64; st<<=1){
    s0 += __shfl_xor(s0, st, 64);
    s1 += __shfl_xor(s1, st, 64);
    s2 += __shfl_xor(s2, st, 64);
    s3 += __shfl_xor(s3, st, 64);
    #pragma unroll
    for (int d=0; d<HIDD; d++){
      ha0[d] += __shfl_xor(ha0[d], st, 64);
      ha1[d] += __shfl_xor(ha1[d], st, 64);
      ha2[d] += __shfl_xor(ha2[d], st, 64);
      ha3[d] += __shfl_xor(ha3[d], st, 64);
    }
  }

  // per-head output y = (Wv2_h . hacc_h + s_h*bv2_h) / (s_h + eps), lane-parallel
  if (lane < H48){
    int h = lane / HIDD;
    float sh  = (h==0) ? s0 : ((h==1) ? s1 : ((h==2) ? s2 : s3));
    float inv = 1.0f / (sh + 1e-16f);
    float acc = sh * bv2[lane];
    #pragma unroll
    for (int dd=0; dd<HIDD; dd++){
      float hv = (h==0) ? ha0[dd] : ((h==1) ? ha1[dd] : ((h==2) ? ha2[dd] : ha3[dd]));
      acc = fmaf(Wv2[dd*H48 + lane], hv, acc);
    }
    yw[wave][lane] = acc * inv;
  }
  __syncthreads();

  // h2 = relu(head-mean + skip2), then logits / A / B epilogue
  float r2[HIDD];
  #pragma unroll
  for (int d=0; d<HIDD; d++){
    float v = yw[wave][d] + yw[wave][HIDD+d] + yw[wave][2*HIDD+d] + yw[wave][3*HIDD+d];
    r2[d] = fmaxf(fmaf(v, 0.25f, skw[wave][d]), 0.f);
  }

  if (lane < NCLSS){
    float acc2 = bn[lane];
    #pragma unroll
    for (int d=0; d<HIDD; d++) acc2 = fmaf(r2[d], Wn[d*NCLSS+lane], acc2);
    outNL[node*NCLSS + lane] = acc2;
  } else if (lane < 4 + HIDD){
    int kk = lane - 4;
    float a = be1[kk];
    #pragma unroll
    for (int d=0; d<HIDD; d++) a = fmaf(r2[d], We1[d*HIDD+kk], a);
    A[node*HIDD + kk] = a;
  } else if (lane < 4 + 2*HIDD){
    int kk = lane - 4 - HIDD;
    float bb = 0.f;
    #pragma unroll
    for (int d=0; d<HIDD; d++) bb = fmaf(r2[d], We1[(HIDD+d)*HIDD+kk], bb);
    B[node*HIDD + kk] = bb;
  }
}

// ==== k_edge: out[i,j,:] = relu(A[i]+B[j]) @ We2 + be2; 2 j x 4 i per thread,
//      float4 stores ==========================================================
__global__ __launch_bounds__(256) void k_edge(
    const float* __restrict__ A, const float* __restrict__ B,
    const float* __restrict__ We2, const float* __restrict__ be2,
    float4* __restrict__ out4)
{
  int jp = blockIdx.x*32 + (threadIdx.x & 31);       // j-pair index, j0 = 2*jp
  int i0 = blockIdx.y*32 + (threadIdx.x >> 5)*4;
  float w0[HIDD], w1[HIDD], B0[HIDD], B1[HIDD];
  #pragma unroll
  for (int kk=0;kk<HIDD;kk++){ w0[kk]=We2[kk*2]; w1[kk]=We2[kk*2+1]; }
  const float* Bj = B + (size_t)jp*2*HIDD;
  #pragma unroll
  for (int kk=0;kk<HIDD;kk++){ B0[kk]=Bj[kk]; B1[kk]=Bj[HIDD+kk]; }
  float b0 = be2[0], b1 = be2[1];
  #pragma unroll
  for (int ii=0; ii<4; ii++){
    int i = i0 + ii;
    const float* Ai = A + i*HIDD;
    float c00=b0, c01=b1, c10=b0, c11=b1;
    #pragma unroll
    for (int kk=0;kk<HIDD;kk++){
      float a = Ai[kk];
      float t0 = fmaxf(a + B0[kk], 0.f);
      float t1 = fmaxf(a + B1[kk], 0.f);
      c00 = fmaf(t0, w0[kk], c00);
      c01 = fmaf(t0, w1[kk], c01);
      c10 = fmaf(t1, w0[kk], c10);
      c11 = fmaf(t1, w1[kk], c11);
    }
    float4 pr; pr.x=c00; pr.y=c01; pr.z=c10; pr.w=c11;
    out4[(size_t)i*(NN/2) + jp] = pr;
  }
}

extern "C" void kernel_launch(void* const* d_in, const int* in_sizes, int n_in,
                              void* d_out, int out_size, void* d_ws, size_t ws_size,
                              hipStream_t stream)
{
  const float* x  = (const float*)d_in[0];
  const int*  ei  = (const int*)d_in[1];
  const int*  t   = (const int*)d_in[3];
  const float* tW = (const float*)d_in[4];  const float* tb = (const float*)d_in[5];
  const float *Wq1=(const float*)d_in[6],  *bq1=(const float*)d_in[7];
  const float *Wk1=(const float*)d_in[8],  *bk1=(const float*)d_in[9];
  const float *Wv1=(const float*)d_in[10], *bv1=(const float*)d_in[11];
  const float *Ws1=(const float*)d_in[12], *bs1=(const float*)d_in[13];
  const float *Wq2=(const float*)d_in[14], *bq2=(const float*)d_in[15];
  const float *Wk2=(const float*)d_in[16], *bk2=(const float*)d_in[17];
  const float *Wv2=(const float*)d_in[18], *bv2=(const float*)d_in[19];
  const float *Ws2=(const float*)d_in[20], *bs2=(const float*)d_in[21];
  const float *Wn =(const float*)d_in[22], *bn =(const float*)d_in[23];
  const float *We1=(const float*)d_in[24], *be1=(const float*)d_in[25];
  const float *We2=(const float*)d_in[26], *be2=(const float*)d_in[27];

  float* ws = (float*)d_ws;
  float* v1t  = ws;                     // 192
  float* sk1t = v1t + NCLSS*H48;        // 48
  float* Stab = sk1t + NCLSS*HIDD;      // 64  (304 floats total, 16B aligned)
  int* cls  = (int*)(Stab + 64);        // 2048
  int* cnt  = cls + NN;                 // 2048   } zeroed together (10240 ints)
  int* ncnt = cnt + NN;                 // 8192   }
  int* slot = ncnt + NN*NCLSS;          // NN*SLOT
  float* A  = (float*)(slot + NN*SLOT); // 24576
  float* B  = A + NN*HIDD;              // 24576

  float* outNL  = (float*)d_out;
  float4* outEL = (float4*)((float*)d_out + NN*NCLSS);

  // 1: tables + score table || zero cnt/ncnt + class extraction
  k_init<<<5, 512, 0, stream>>>(x, t, tW, tb,
                                Wq1,bq1, Wk1,bk1, Wv1,bv1, Ws1,bs1,
                                v1t, sk1t, Stab, cls, cnt);
  // 2: slot scatter + class histogram
  k_fill<<<EE/512, 512, 0, stream>>>(ei, cls, cnt, ncnt, slot);
  // 3: fused layer-1-closed-form + layer-2 attention + logits/A/B
  k_mega<<<NN/8, 512, 0, stream>>>(cls, cnt, ncnt, slot, v1t, sk1t, Stab,
                                   Wq2,bq2, Wk2,bk2, Wv2,bv2, Ws2,bs2,
                                   Wn,bn, We1,be1, A, B, outNL);
  // 4: dense pair MLP
  k_edge<<<dim3(32, 64), 256, 0, stream>>>(A, B, We2, be2, outEL);
}

// Round 11
// 55.348 us; speedup vs baseline: 1.2718x; 1.2718x over previous
//
#include <hip/hip_runtime.h>

#define NN 2048
#define EE 65536
#define HIDD 12
#define NH 4
#define TEDD 16
#define NCLSS 4
#define H48 48
#define SLOT 128   // fixed edge-slots per dst (max degree ~55 << 128)

__device__ __forceinline__ float read_t(const int* p){
  int i = *p;
  if (i >= 0 && i < 100000) return (float)i;   // int-encoded scalar (expected)
  return __int_as_float(i);                     // defensive: float-encoded scalar
}

// layer-1 output h1[12] from (class cd, neighbor-class counts nf0..3), via the
// 4-row class tables. Exact same math as per-node reference evaluation.
__device__ __forceinline__ void l1h(int cd, float nf0, float nf1, float nf2, float nf3,
    const float* SL, const float* vL, const float* skL, float r[HIDD])
{
  #pragma unroll
  for (int d=0; d<HIDD; d++) r[d] = 0.f;
  #pragma unroll
  for (int h=0; h<NH; h++){
    float s0 = SL[cd*16 + h*4 + 0];
    float s1 = SL[cd*16 + h*4 + 1];
    float s2 = SL[cd*16 + h*4 + 2];
    float s3 = SL[cd*16 + h*4 + 3];
    float m = -INFINITY;
    if (nf0 > 0.f) m = fmaxf(m, s0);
    if (nf1 > 0.f) m = fmaxf(m, s1);
    if (nf2 > 0.f) m = fmaxf(m, s2);
    if (nf3 > 0.f) m = fmaxf(m, s3);
    float w0 = (nf0 > 0.f) ? nf0*__expf(s0 - m) : 0.f;
    float w1 = (nf1 > 0.f) ? nf1*__expf(s1 - m) : 0.f;
    float w2 = (nf2 > 0.f) ? nf2*__expf(s2 - m) : 0.f;
    float w3 = (nf3 > 0.f) ? nf3*__expf(s3 - m) : 0.f;
    float inv = 1.0f / (w0 + w1 + w2 + w3 + 1e-16f);
    #pragma unroll
    for (int d=0; d<HIDD; d++){
      float num = w0*vL[0*H48 + h*HIDD + d] + w1*vL[1*H48 + h*HIDD + d]
                + w2*vL[2*H48 + h*HIDD + d] + w3*vL[3*H48 + h*HIDD + d];
      r[d] = fmaf(num, inv, r[d]);
    }
  }
  #pragma unroll
  for (int d=0; d<HIDD; d++)
    r[d] = fmaxf(fmaf(r[d], 0.25f, skL[cd*HIDD + d]), 0.f);
}

// ==== k_init: block 0 = layer-1 class tables + 4x4x4 score table;
//              blocks 1-4 = zero cnt+ncnt (10240 ints) + class extraction =====
__global__ __launch_bounds__(512) void k_init(
    const float* __restrict__ x, const int* __restrict__ t,
    const float* __restrict__ tW, const float* __restrict__ tb,
    const float* __restrict__ Wq, const float* __restrict__ bq,
    const float* __restrict__ Wk, const float* __restrict__ bk,
    const float* __restrict__ Wv, const float* __restrict__ bv,
    const float* __restrict__ Ws, const float* __restrict__ bs,
    float* __restrict__ v1t, float* __restrict__ sk1t, float* __restrict__ Stab,
    int* __restrict__ cls, int* __restrict__ zr)
{
  const int tid = threadIdx.x;
  if (blockIdx.x > 0){
    int g = (blockIdx.x - 1)*512 + tid;               // 0..2047
    #pragma unroll
    for (int i=g; i<NN*(1+NCLSS); i+=2048) zr[i] = 0; // cnt + ncnt
    const float* xr = x + g*NCLSS;
    int c = (xr[1]>0.5f) ? 1 : ((xr[2]>0.5f) ? 2 : ((xr[3]>0.5f) ? 3 : 0));
    cls[g] = c;
    return;
  }

  __shared__ float teL[TEDD];
  __shared__ float q1tL[NCLSS][H48];
  __shared__ float k1tL[NCLSS][H48];
  if (tid < TEDD){
    float tf = read_t(t) / 100.0f;
    float lsc = __logf(10000.0f) / 7.0f;
    float emb[TEDD];
    #pragma unroll
    for (int i=0;i<8;i++){
      float vv = tf * __expf(-(float)i * lsc);
      emb[i] = __sinf(vv); emb[i+8] = __cosf(vv);
    }
    float acc = tb[tid];
    #pragma unroll
    for (int kk=0;kk<TEDD;kk++) acc = fmaf(emb[kk], tW[kk*TEDD+tid], acc);
    teL[tid] = acc;
  }
  __syncthreads();

  if (tid < NCLSS*H48){
    int c = tid / H48, j = tid - c*H48;
    // one-hot fma adds of 0.0 are exact no-ops -> identical to per-node qkv1
    float aq = bq[j] + Wq[c*H48+j];
    float ak = bk[j] + Wk[c*H48+j];
    float av = bv[j] + Wv[c*H48+j];
    #pragma unroll
    for (int d=0; d<TEDD; d++){
      float te = teL[d];
      aq = fmaf(te, Wq[(NCLSS+d)*H48+j], aq);
      ak = fmaf(te, Wk[(NCLSS+d)*H48+j], ak);
      av = fmaf(te, Wv[(NCLSS+d)*H48+j], av);
    }
    q1tL[c][j] = aq; k1tL[c][j] = ak; v1t[c*H48+j] = av;
  } else if (tid < NCLSS*H48 + NCLSS*HIDD){
    int u = tid - NCLSS*H48;
    int c = u / HIDD, j = u - c*HIDD;
    float as = bs[j] + Ws[c*HIDD+j];
    #pragma unroll
    for (int d=0; d<TEDD; d++) as = fmaf(teL[d], Ws[(NCLSS+d)*HIDD+j], as);
    sk1t[c*HIDD+j] = as;
  }
  __syncthreads();

  if (tid < 64){
    int cd = tid >> 4, h = (tid >> 2) & 3, c = tid & 3;
    float s = 0.f;
    #pragma unroll
    for (int d=0; d<HIDD; d++) s = fmaf(q1tL[cd][h*HIDD+d], k1tL[c][h*HIDD+d], s);
    Stab[tid] = s * 0.28867513459481287f;   // 1/sqrt(12)
  }
}

// ==== k_fill: edge-table scatter + per-dst class histogram ===================
__global__ __launch_bounds__(512) void k_fill(
    const int* __restrict__ ei, const int* __restrict__ cls,
    int* __restrict__ cnt, int* __restrict__ ncnt, int* __restrict__ slot)
{
  int e = blockIdx.x*512 + threadIdx.x;
  int s = ei[e], d = ei[EE + e];
  int pos = atomicAdd(&cnt[d], 1);
  if (pos < SLOT) slot[d*SLOT + pos] = s;
  atomicAdd(&ncnt[d*NCLSS + cls[s]], 1);
}

// ==== k_node: fused layer-1-closed-form + layer-2 attention + epilogue.
//      One wave per node; 16 lanes per layer-2 head (lane = head*16+sub) so
//      each lane's online-softmax state is only acc[12]+m+s (no spill). ======
__global__ __launch_bounds__(512) void k_node(
    const int* __restrict__ cls, const int* __restrict__ cnt,
    const int* __restrict__ ncnt, const int* __restrict__ slot,
    const float* __restrict__ v1t, const float* __restrict__ sk1t,
    const float* __restrict__ Stab,
    const float* __restrict__ Wq2, const float* __restrict__ bq2,
    const float* __restrict__ Wk2, const float* __restrict__ bk2,
    const float* __restrict__ Wv2, const float* __restrict__ bv2,
    const float* __restrict__ Ws2, const float* __restrict__ bs2,
    const float* __restrict__ Wn, const float* __restrict__ bn,
    const float* __restrict__ We1, const float* __restrict__ be1,
    float* __restrict__ A, float* __restrict__ B, float* __restrict__ outNL)
{
  const int tid  = threadIdx.x;
  const int wave = tid >> 6;
  const int lane = tid & 63;
  const int head = lane >> 4;
  const int sub  = lane & 15;
  const int node = blockIdx.x*8 + wave;

  __shared__ float SL[64], vL[NCLSS*H48], skL[NCLSS*HIDD];
  __shared__ float qw[8][H48], uw[8][H48], c0w[8][NH], skw[8][HIDD], yw[8][H48];
  if (tid < 64) SL[tid] = Stab[tid];
  else if (tid < 64 + NCLSS*H48) vL[tid-64] = v1t[tid-64];
  else if (tid < 64 + NCLSS*H48 + NCLSS*HIDD) skL[tid-64-NCLSS*H48] = sk1t[tid-64-NCLSS*H48];
  __syncthreads();

  // own node: layer-1 h from tables (all lanes, redundant)
  const int cd = cls[node];
  const int4 nc = *(const int4*)(ncnt + node*NCLSS);
  {
    float r1[HIDD];
    l1h(cd, (float)nc.x, (float)nc.y, (float)nc.z, (float)nc.w, SL, vL, skL, r1);

    // q2 row + skip2 for this node -> LDS
    if (lane < H48){
      float aq = bq2[lane];
      #pragma unroll
      for (int d=0; d<HIDD; d++) aq = fmaf(r1[d], Wq2[d*H48+lane], aq);
      qw[wave][lane] = aq;
    } else if (lane < H48+HIDD){
      int j = lane - H48;
      float as = bs2[j];
      #pragma unroll
      for (int d=0; d<HIDD; d++) as = fmaf(r1[d], Ws2[d*HIDD+j], as);
      skw[wave][j] = as;
    }
  }
  __syncthreads();

  // u_h[d] = sum_j Wk2[d][h*12+j]*q2[h*12+j]; c0_h = q2_h . bk2_h
  if (lane < H48){
    int h = lane / HIDD, dd = lane - h*HIDD;
    float u = 0.f;
    #pragma unroll
    for (int jj=0; jj<HIDD; jj++)
      u = fmaf(Wk2[dd*H48 + h*HIDD + jj], qw[wave][h*HIDD+jj], u);
    uw[wave][lane] = u;
  } else if (lane < H48+NH){
    int h = lane - H48;
    float c0 = 0.f;
    #pragma unroll
    for (int jj=0; jj<HIDD; jj++)
      c0 = fmaf(qw[wave][h*HIDD+jj], bk2[h*HIDD+jj], c0);
    c0w[wave][h] = c0;
  }
  __syncthreads();

  // neighbor sweep: 16-lane group per head, per-lane online softmax
  const float ksc = 0.28867513459481287f;
  float m = -INFINITY, s = 0.f;
  float acc[HIDD];
  #pragma unroll
  for (int d=0; d<HIDD; d++) acc[d] = 0.f;

  int dg = cnt[node]; dg = (dg > SLOT) ? SLOT : dg;
  for (int i=sub; i<dg; i+=16){
    int src = slot[node*SLOT + i];
    int cs = cls[src];
    const int4 snc = *(const int4*)(ncnt + src*NCLSS);
    float hs[HIDD];
    l1h(cs, (float)snc.x, (float)snc.y, (float)snc.z, (float)snc.w, SL, vL, skL, hs);

    float sc = c0w[wave][head];
    #pragma unroll
    for (int dd=0; dd<HIDD; dd++) sc = fmaf(uw[wave][head*HIDD+dd], hs[dd], sc);
    sc *= ksc;

    if (sc > m){
      float f = __expf(m - sc);        // exp(-inf - finite) = 0 on first hit
      s *= f;
      #pragma unroll
      for (int d=0; d<HIDD; d++) acc[d] *= f;
      m = sc;
    }
    float w = __expf(sc - m);
    s += w;
    #pragma unroll
    for (int d=0; d<HIDD; d++) acc[d] = fmaf(w, hs[d], acc[d]);
  }

  // merge the 16 lanes of this head group (flash-style)
  float mg = m;
  #pragma unroll
  for (int st=1; st<16; st<<=1) mg = fmaxf(mg, __shfl_xor(mg, st, 64));
  {
    float f = (m > -INFINITY) ? __expf(m - mg) : 0.f;   // dg==0 guard
    s *= f;
    #pragma unroll
    for (int d=0; d<HIDD; d++) acc[d] *= f;
  }
  #pragma unroll
  for (int st=1; st<16; st<<=1){
    s += __shfl_xor(s, st, 64);
    #pragma unroll
    for (int d=0; d<HIDD; d++) acc[d] += __shfl_xor(acc[d], st, 64);
  }

  // per-head y[h*12+sub] = (Wv2_h . hacc_h + s_h*bv2_h)/(s_h+eps)
  if (sub < HIDD){
    int out = head*HIDD + sub;
    float inv = 1.0f / (s + 1e-16f);
    float a2 = s * bv2[out];
    #pragma unroll
    for (int dd=0; dd<HIDD; dd++) a2 = fmaf(Wv2[dd*H48 + out], acc[dd], a2);
    yw[wave][out] = a2 * inv;
  }
  __syncthreads();

  // h2 = relu(head-mean + skip2); epilogue logits / A / B
  float r2[HIDD];
  #pragma unroll
  for (int d=0; d<HIDD; d++){
    float v = yw[wave][d] + yw[wave][HIDD+d] + yw[wave][2*HIDD+d] + yw[wave][3*HIDD+d];
    r2[d] = fmaxf(fmaf(v, 0.25f, skw[wave][d]), 0.f);
  }

  if (lane < NCLSS){
    float acc2 = bn[lane];
    #pragma unroll
    for (int d=0; d<HIDD; d++) acc2 = fmaf(r2[d], Wn[d*NCLSS+lane], acc2);
    outNL[node*NCLSS + lane] = acc2;
  } else if (lane < 4 + HIDD){
    int kk = lane - 4;
    float a = be1[kk];
    #pragma unroll
    for (int d=0; d<HIDD; d++) a = fmaf(r2[d], We1[d*HIDD+kk], a);
    A[node*HIDD + kk] = a;
  } else if (lane < 4 + 2*HIDD){
    int kk = lane - 4 - HIDD;
    float bb = 0.f;
    #pragma unroll
    for (int d=0; d<HIDD; d++) bb = fmaf(r2[d], We1[(HIDD+d)*HIDD+kk], bb);
    B[node*HIDD + kk] = bb;
  }
}

// ==== k_edge: out[i,j,:] = relu(A[i]+B[j]) @ We2 + be2; 2 j x 4 i per thread,
//      float4 stores ==========================================================
__global__ __launch_bounds__(256) void k_edge(
    const float* __restrict__ A, const float* __restrict__ B,
    const float* __restrict__ We2, const float* __restrict__ be2,
    float4* __restrict__ out4)
{
  int jp = blockIdx.x*32 + (threadIdx.x & 31);       // j-pair index, j0 = 2*jp
  int i0 = blockIdx.y*32 + (threadIdx.x >> 5)*4;
  float w0[HIDD], w1[HIDD], B0[HIDD], B1[HIDD];
  #pragma unroll
  for (int kk=0;kk<HIDD;kk++){ w0[kk]=We2[kk*2]; w1[kk]=We2[kk*2+1]; }
  const float* Bj = B + (size_t)jp*2*HIDD;
  #pragma unroll
  for (int kk=0;kk<HIDD;kk++){ B0[kk]=Bj[kk]; B1[kk]=Bj[HIDD+kk]; }
  float b0 = be2[0], b1 = be2[1];
  #pragma unroll
  for (int ii=0; ii<4; ii++){
    int i = i0 + ii;
    const float* Ai = A + i*HIDD;
    float c00=b0, c01=b1, c10=b0, c11=b1;
    #pragma unroll
    for (int kk=0;kk<HIDD;kk++){
      float a = Ai[kk];
      float t0 = fmaxf(a + B0[kk], 0.f);
      float t1 = fmaxf(a + B1[kk], 0.f);
      c00 = fmaf(t0, w0[kk], c00);
      c01 = fmaf(t0, w1[kk], c01);
      c10 = fmaf(t1, w0[kk], c10);
      c11 = fmaf(t1, w1[kk], c11);
    }
    float4 pr; pr.x=c00; pr.y=c01; pr.z=c10; pr.w=c11;
    out4[(size_t)i*(NN/2) + jp] = pr;
  }
}

extern "C" void kernel_launch(void* const* d_in, const int* in_sizes, int n_in,
                              void* d_out, int out_size, void* d_ws, size_t ws_size,
                              hipStream_t stream)
{
  const float* x  = (const float*)d_in[0];
  const int*  ei  = (const int*)d_in[1];
  const int*  t   = (const int*)d_in[3];
  const float* tW = (const float*)d_in[4];  const float* tb = (const float*)d_in[5];
  const float *Wq1=(const float*)d_in[6],  *bq1=(const float*)d_in[7];
  const float *Wk1=(const float*)d_in[8],  *bk1=(const float*)d_in[9];
  const float *Wv1=(const float*)d_in[10], *bv1=(const float*)d_in[11];
  const float *Ws1=(const float*)d_in[12], *bs1=(const float*)d_in[13];
  const float *Wq2=(const float*)d_in[14], *bq2=(const float*)d_in[15];
  const float *Wk2=(const float*)d_in[16], *bk2=(const float*)d_in[17];
  const float *Wv2=(const float*)d_in[18], *bv2=(const float*)d_in[19];
  const float *Ws2=(const float*)d_in[20], *bs2=(const float*)d_in[21];
  const float *Wn =(const float*)d_in[22], *bn =(const float*)d_in[23];
  const float *We1=(const float*)d_in[24], *be1=(const float*)d_in[25];
  const float *We2=(const float*)d_in[26], *be2=(const float*)d_in[27];

  float* ws = (float*)d_ws;
  float* v1t  = ws;                     // 192
  float* sk1t = v1t + NCLSS*H48;        // 48
  float* Stab = sk1t + NCLSS*HIDD;      // 64  (304 floats, 16B aligned)
  int* cls  = (int*)(Stab + 64);        // 2048
  int* cnt  = cls + NN;                 // 2048   } zeroed together (10240 ints)
  int* ncnt = cnt + NN;                 // 8192   }
  int* slot = ncnt + NN*NCLSS;          // NN*SLOT
  float* A  = (float*)(slot + NN*SLOT); // 24576
  float* B  = A + NN*HIDD;              // 24576

  float* outNL  = (float*)d_out;
  float4* outEL = (float4*)((float*)d_out + NN*NCLSS);

  // 1: tables + score table || zero cnt/ncnt + class extraction
  k_init<<<5, 512, 0, stream>>>(x, t, tW, tb,
                                Wq1,bq1, Wk1,bk1, Wv1,bv1, Ws1,bs1,
                                v1t, sk1t, Stab, cls, cnt);
  // 2: slot scatter + class histogram
  k_fill<<<EE/512, 512, 0, stream>>>(ei, cls, cnt, ncnt, slot);
  // 3: fused node pipeline (layer-1 closed form + layer-2 attn + logits/A/B)
  k_node<<<NN/8, 512, 0, stream>>>(cls, cnt, ncnt, slot, v1t, sk1t, Stab,
                                   Wq2,bq2, Wk2,bk2, Wv2,bv2, Ws2,bs2,
                                   Wn,bn, We1,be1, A, B, outNL);
  // 4: dense pair MLP
  k_edge<<<dim3(32, 64), 256, 0, stream>>>(A, B, We2, be2, outEL);
}

// Round 12
// 47.036 us; speedup vs baseline: 1.4965x; 1.1767x over previous
//
#include <hip/hip_runtime.h>

#define NN 2048
#define EE 65536
#define HIDD 12
#define NH 4
#define TEDD 16
#define NCLSS 4
#define H48 48
#define SLOT 128   // fixed edge-slots per dst (max degree ~55 << 128)

__device__ __forceinline__ float read_t(const int* p){
  int i = *p;
  if (i >= 0 && i < 100000) return (float)i;   // int-encoded scalar (expected)
  return __int_as_float(i);                     // defensive: float-encoded scalar
}

// layer-1 output h1[12] from (class cd, neighbor-class counts nf0..3), via the
// 4-row class tables. Exact same math as per-node reference evaluation.
__device__ __forceinline__ void l1h(int cd, float nf0, float nf1, float nf2, float nf3,
    const float* SL, const float* vL, const float* skL, float r[HIDD])
{
  #pragma unroll
  for (int d=0; d<HIDD; d++) r[d] = 0.f;
  #pragma unroll
  for (int h=0; h<NH; h++){
    float s0 = SL[cd*16 + h*4 + 0];
    float s1 = SL[cd*16 + h*4 + 1];
    float s2 = SL[cd*16 + h*4 + 2];
    float s3 = SL[cd*16 + h*4 + 3];
    float m = -INFINITY;
    if (nf0 > 0.f) m = fmaxf(m, s0);
    if (nf1 > 0.f) m = fmaxf(m, s1);
    if (nf2 > 0.f) m = fmaxf(m, s2);
    if (nf3 > 0.f) m = fmaxf(m, s3);
    float w0 = (nf0 > 0.f) ? nf0*__expf(s0 - m) : 0.f;
    float w1 = (nf1 > 0.f) ? nf1*__expf(s1 - m) : 0.f;
    float w2 = (nf2 > 0.f) ? nf2*__expf(s2 - m) : 0.f;
    float w3 = (nf3 > 0.f) ? nf3*__expf(s3 - m) : 0.f;
    float inv = 1.0f / (w0 + w1 + w2 + w3 + 1e-16f);
    #pragma unroll
    for (int d=0; d<HIDD; d++){
      float num = w0*vL[0*H48 + h*HIDD + d] + w1*vL[1*H48 + h*HIDD + d]
                + w2*vL[2*H48 + h*HIDD + d] + w3*vL[3*H48 + h*HIDD + d];
      r[d] = fmaf(num, inv, r[d]);
    }
  }
  #pragma unroll
  for (int d=0; d<HIDD; d++)
    r[d] = fmaxf(fmaf(r[d], 0.25f, skL[cd*HIDD + d]), 0.f);
}

// ==== k_init: block 0 = layer-1 class tables + 4x4x4 score table;
//              blocks 1-4 = zero cnt+ncnt (10240 ints) + class extraction =====
__global__ __launch_bounds__(512) void k_init(
    const float* __restrict__ x, const int* __restrict__ t,
    const float* __restrict__ tW, const float* __restrict__ tb,
    const float* __restrict__ Wq, const float* __restrict__ bq,
    const float* __restrict__ Wk, const float* __restrict__ bk,
    const float* __restrict__ Wv, const float* __restrict__ bv,
    const float* __restrict__ Ws, const float* __restrict__ bs,
    float* __restrict__ v1t, float* __restrict__ sk1t, float* __restrict__ Stab,
    int* __restrict__ cls, int* __restrict__ zr)
{
  const int tid = threadIdx.x;
  if (blockIdx.x > 0){
    int g = (blockIdx.x - 1)*512 + tid;               // 0..2047
    #pragma unroll
    for (int i=g; i<NN*(1+NCLSS); i+=2048) zr[i] = 0; // cnt + ncnt
    const float* xr = x + g*NCLSS;
    int c = (xr[1]>0.5f) ? 1 : ((xr[2]>0.5f) ? 2 : ((xr[3]>0.5f) ? 3 : 0));
    cls[g] = c;
    return;
  }

  __shared__ float teL[TEDD];
  __shared__ float q1tL[NCLSS][H48];
  __shared__ float k1tL[NCLSS][H48];
  if (tid < TEDD){
    float tf = read_t(t) / 100.0f;
    float lsc = __logf(10000.0f) / 7.0f;
    float emb[TEDD];
    #pragma unroll
    for (int i=0;i<8;i++){
      float vv = tf * __expf(-(float)i * lsc);
      emb[i] = __sinf(vv); emb[i+8] = __cosf(vv);
    }
    float acc = tb[tid];
    #pragma unroll
    for (int kk=0;kk<TEDD;kk++) acc = fmaf(emb[kk], tW[kk*TEDD+tid], acc);
    teL[tid] = acc;
  }
  __syncthreads();

  if (tid < NCLSS*H48){
    int c = tid / H48, j = tid - c*H48;
    // one-hot fma adds of 0.0 are exact no-ops -> identical to per-node qkv1
    float aq = bq[j] + Wq[c*H48+j];
    float ak = bk[j] + Wk[c*H48+j];
    float av = bv[j] + Wv[c*H48+j];
    #pragma unroll
    for (int d=0; d<TEDD; d++){
      float te = teL[d];
      aq = fmaf(te, Wq[(NCLSS+d)*H48+j], aq);
      ak = fmaf(te, Wk[(NCLSS+d)*H48+j], ak);
      av = fmaf(te, Wv[(NCLSS+d)*H48+j], av);
    }
    q1tL[c][j] = aq; k1tL[c][j] = ak; v1t[c*H48+j] = av;
  } else if (tid < NCLSS*H48 + NCLSS*HIDD){
    int u = tid - NCLSS*H48;
    int c = u / HIDD, j = u - c*HIDD;
    float as = bs[j] + Ws[c*HIDD+j];
    #pragma unroll
    for (int d=0; d<TEDD; d++) as = fmaf(teL[d], Ws[(NCLSS+d)*HIDD+j], as);
    sk1t[c*HIDD+j] = as;
  }
  __syncthreads();

  if (tid < 64){
    int cd = tid >> 4, h = (tid >> 2) & 3, c = tid & 3;
    float s = 0.f;
    #pragma unroll
    for (int d=0; d<HIDD; d++) s = fmaf(q1tL[cd][h*HIDD+d], k1tL[c][h*HIDD+d], s);
    Stab[tid] = s * 0.28867513459481287f;   // 1/sqrt(12)
  }
}

// ==== k_fill: edge-table scatter + per-dst class histogram ===================
__global__ __launch_bounds__(512) void k_fill(
    const int* __restrict__ ei, const int* __restrict__ cls,
    int* __restrict__ cnt, int* __restrict__ ncnt, int* __restrict__ slot)
{
  int e = blockIdx.x*512 + threadIdx.x;
  int s = ei[e], d = ei[EE + e];
  int pos = atomicAdd(&cnt[d], 1);
  if (pos < SLOT) slot[d*SLOT + pos] = s;
  atomicAdd(&ncnt[d*NCLSS + cls[s]], 1);
}

// ==== k_h1: flat thread-per-node layer-1 closed form -> h1[NN][12] ===========
__global__ __launch_bounds__(512) void k_h1(
    const int* __restrict__ cls, const int* __restrict__ ncnt,
    const float* __restrict__ v1t, const float* __restrict__ sk1t,
    const float* __restrict__ Stab, float* __restrict__ h1)
{
  __shared__ float SL[64], vL[NCLSS*H48], skL[NCLSS*HIDD];
  const int tid = threadIdx.x;
  if (tid < 64) SL[tid] = Stab[tid];
  else if (tid < 64 + NCLSS*H48) vL[tid-64] = v1t[tid-64];
  else if (tid < 64 + NCLSS*H48 + NCLSS*HIDD) skL[tid-64-NCLSS*H48] = sk1t[tid-64-NCLSS*H48];
  __syncthreads();

  int n = blockIdx.x*512 + tid;
  int cd = cls[n];
  const int4 nc = *(const int4*)(ncnt + n*NCLSS);
  float r[HIDD];
  l1h(cd, (float)nc.x, (float)nc.y, (float)nc.z, (float)nc.w, SL, vL, skL, r);
  float4* hp = (float4*)(h1 + n*HIDD);
  hp[0] = make_float4(r[0], r[1], r[2], r[3]);
  hp[1] = make_float4(r[4], r[5], r[6], r[7]);
  hp[2] = make_float4(r[8], r[9], r[10], r[11]);
}

// ==== k_attn2: u-factored layer-2 attention over materialized h1 + epilogue.
//      One wave per node; 16 lanes per head; per-lane state acc[12]+m+s. =====
__global__ __launch_bounds__(512) void k_attn2(
    const int* __restrict__ cnt, const int* __restrict__ slot,
    const float* __restrict__ h1,
    const float* __restrict__ Wq2, const float* __restrict__ bq2,
    const float* __restrict__ Wk2, const float* __restrict__ bk2,
    const float* __restrict__ Wv2, const float* __restrict__ bv2,
    const float* __restrict__ Ws2, const float* __restrict__ bs2,
    const float* __restrict__ Wn, const float* __restrict__ bn,
    const float* __restrict__ We1, const float* __restrict__ be1,
    float* __restrict__ A, float* __restrict__ B, float* __restrict__ outNL)
{
  const int tid  = threadIdx.x;
  const int wave = tid >> 6;
  const int lane = tid & 63;
  const int head = lane >> 4;
  const int sub  = lane & 15;
  const int node = blockIdx.x*8 + wave;

  __shared__ float hw[8][HIDD];
  __shared__ float qw[8][H48], uw[8][H48], c0w[8][NH], skw[8][HIDD], yw[8][H48];

  if (lane < HIDD) hw[wave][lane] = h1[node*HIDD + lane];
  __syncthreads();

  // q2 row + skip2 for this node -> LDS (from own h1)
  if (lane < H48){
    float aq = bq2[lane];
    #pragma unroll
    for (int d=0; d<HIDD; d++) aq = fmaf(hw[wave][d], Wq2[d*H48+lane], aq);
    qw[wave][lane] = aq;
  } else if (lane < H48+HIDD){
    int j = lane - H48;
    float as = bs2[j];
    #pragma unroll
    for (int d=0; d<HIDD; d++) as = fmaf(hw[wave][d], Ws2[d*HIDD+j], as);
    skw[wave][j] = as;
  }
  __syncthreads();

  // u_h[d] = sum_j Wk2[d][h*12+j]*q2[h*12+j]; c0_h = q2_h . bk2_h
  if (lane < H48){
    int h = lane / HIDD, dd = lane - h*HIDD;
    float u = 0.f;
    #pragma unroll
    for (int jj=0; jj<HIDD; jj++)
      u = fmaf(Wk2[dd*H48 + h*HIDD + jj], qw[wave][h*HIDD+jj], u);
    uw[wave][lane] = u;
  } else if (lane < H48+NH){
    int h = lane - H48;
    float c0 = 0.f;
    #pragma unroll
    for (int jj=0; jj<HIDD; jj++)
      c0 = fmaf(qw[wave][h*HIDD+jj], bk2[h*HIDD+jj], c0);
    c0w[wave][h] = c0;
  }
  __syncthreads();

  // neighbor sweep: 16-lane group per head, per-lane online softmax over h1
  const float ksc = 0.28867513459481287f;
  float m = -INFINITY, s = 0.f;
  float acc[HIDD];
  #pragma unroll
  for (int d=0; d<HIDD; d++) acc[d] = 0.f;

  int dg = cnt[node]; dg = (dg > SLOT) ? SLOT : dg;
  for (int i=sub; i<dg; i+=16){
    int src = slot[node*SLOT + i];
    const float4* hp = (const float4*)(h1 + src*HIDD);
    float4 hA = hp[0], hB = hp[1], hC = hp[2];
    float hs[HIDD] = {hA.x,hA.y,hA.z,hA.w, hB.x,hB.y,hB.z,hB.w, hC.x,hC.y,hC.z,hC.w};

    float sc = c0w[wave][head];
    #pragma unroll
    for (int dd=0; dd<HIDD; dd++) sc = fmaf(uw[wave][head*HIDD+dd], hs[dd], sc);
    sc *= ksc;

    if (sc > m){
      float f = __expf(m - sc);        // exp(-inf - finite) = 0 on first hit
      s *= f;
      #pragma unroll
      for (int d=0; d<HIDD; d++) acc[d] *= f;
      m = sc;
    }
    float w = __expf(sc - m);
    s += w;
    #pragma unroll
    for (int d=0; d<HIDD; d++) acc[d] = fmaf(w, hs[d], acc[d]);
  }

  // merge the 16 lanes of this head group (flash-style)
  float mg = m;
  #pragma unroll
  for (int st=1; st<16; st<<=1) mg = fmaxf(mg, __shfl_xor(mg, st, 64));
  {
    float f = (m > -INFINITY) ? __expf(m - mg) : 0.f;   // dg==0 guard
    s *= f;
    #pragma unroll
    for (int d=0; d<HIDD; d++) acc[d] *= f;
  }
  #pragma unroll
  for (int st=1; st<16; st<<=1){
    s += __shfl_xor(s, st, 64);
    #pragma unroll
    for (int d=0; d<HIDD; d++) acc[d] += __shfl_xor(acc[d], st, 64);
  }

  // per-head y[h*12+sub] = (Wv2_h . hacc_h + s_h*bv2_h)/(s_h+eps)
  if (sub < HIDD){
    int out = head*HIDD + sub;
    float inv = 1.0f / (s + 1e-16f);
    float a2 = s * bv2[out];
    #pragma unroll
    for (int dd=0; dd<HIDD; dd++) a2 = fmaf(Wv2[dd*H48 + out], acc[dd], a2);
    yw[wave][out] = a2 * inv;
  }
  __syncthreads();

  // h2 = relu(head-mean + skip2); epilogue logits / A / B
  float r2[HIDD];
  #pragma unroll
  for (int d=0; d<HIDD; d++){
    float v = yw[wave][d] + yw[wave][HIDD+d] + yw[wave][2*HIDD+d] + yw[wave][3*HIDD+d];
    r2[d] = fmaxf(fmaf(v, 0.25f, skw[wave][d]), 0.f);
  }

  if (lane < NCLSS){
    float acc2 = bn[lane];
    #pragma unroll
    for (int d=0; d<HIDD; d++) acc2 = fmaf(r2[d], Wn[d*NCLSS+lane], acc2);
    outNL[node*NCLSS + lane] = acc2;
  } else if (lane < 4 + HIDD){
    int kk = lane - 4;
    float a = be1[kk];
    #pragma unroll
    for (int d=0; d<HIDD; d++) a = fmaf(r2[d], We1[d*HIDD+kk], a);
    A[node*HIDD + kk] = a;
  } else if (lane < 4 + 2*HIDD){
    int kk = lane - 4 - HIDD;
    float bb = 0.f;
    #pragma unroll
    for (int d=0; d<HIDD; d++) bb = fmaf(r2[d], We1[(HIDD+d)*HIDD+kk], bb);
    B[node*HIDD + kk] = bb;
  }
}

// ==== k_edge: out[i,j,:] = relu(A[i]+B[j]) @ We2 + be2; 2 j x 4 i per thread,
//      float4 stores ==========================================================
__global__ __launch_bounds__(256) void k_edge(
    const float* __restrict__ A, const float* __restrict__ B,
    const float* __restrict__ We2, const float* __restrict__ be2,
    float4* __restrict__ out4)
{
  int jp = blockIdx.x*32 + (threadIdx.x & 31);       // j-pair index, j0 = 2*jp
  int i0 = blockIdx.y*32 + (threadIdx.x >> 5)*4;
  float w0[HIDD], w1[HIDD], B0[HIDD], B1[HIDD];
  #pragma unroll
  for (int kk=0;kk<HIDD;kk++){ w0[kk]=We2[kk*2]; w1[kk]=We2[kk*2+1]; }
  const float* Bj = B + (size_t)jp*2*HIDD;
  #pragma unroll
  for (int kk=0;kk<HIDD;kk++){ B0[kk]=Bj[kk]; B1[kk]=Bj[HIDD+kk]; }
  float b0 = be2[0], b1 = be2[1];
  #pragma unroll
  for (int ii=0; ii<4; ii++){
    int i = i0 + ii;
    const float* Ai = A + i*HIDD;
    float c00=b0, c01=b1, c10=b0, c11=b1;
    #pragma unroll
    for (int kk=0;kk<HIDD;kk++){
      float a = Ai[kk];
      float t0 = fmaxf(a + B0[kk], 0.f);
      float t1 = fmaxf(a + B1[kk], 0.f);
      c00 = fmaf(t0, w0[kk], c00);
      c01 = fmaf(t0, w1[kk], c01);
      c10 = fmaf(t1, w0[kk], c10);
      c11 = fmaf(t1, w1[kk], c11);
    }
    float4 pr; pr.x=c00; pr.y=c01; pr.z=c10; pr.w=c11;
    out4[(size_t)i*(NN/2) + jp] = pr;
  }
}

extern "C" void kernel_launch(void* const* d_in, const int* in_sizes, int n_in,
                              void* d_out, int out_size, void* d_ws, size_t ws_size,
                              hipStream_t stream)
{
  const float* x  = (const float*)d_in[0];
  const int*  ei  = (const int*)d_in[1];
  const int*  t   = (const int*)d_in[3];
  const float* tW = (const float*)d_in[4];  const float* tb = (const float*)d_in[5];
  const float *Wq1=(const float*)d_in[6],  *bq1=(const float*)d_in[7];
  const float *Wk1=(const float*)d_in[8],  *bk1=(const float*)d_in[9];
  const float *Wv1=(const float*)d_in[10], *bv1=(const float*)d_in[11];
  const float *Ws1=(const float*)d_in[12], *bs1=(const float*)d_in[13];
  const float *Wq2=(const float*)d_in[14], *bq2=(const float*)d_in[15];
  const float *Wk2=(const float*)d_in[16], *bk2=(const float*)d_in[17];
  const float *Wv2=(const float*)d_in[18], *bv2=(const float*)d_in[19];
  const float *Ws2=(const float*)d_in[20], *bs2=(const float*)d_in[21];
  const float *Wn =(const float*)d_in[22], *bn =(const float*)d_in[23];
  const float *We1=(const float*)d_in[24], *be1=(const float*)d_in[25];
  const float *We2=(const float*)d_in[26], *be2=(const float*)d_in[27];

  float* ws = (float*)d_ws;
  float* v1t  = ws;                     // 192
  float* sk1t = v1t + NCLSS*H48;        // 48
  float* Stab = sk1t + NCLSS*HIDD;      // 64  (304 floats, 16B aligned)
  int* cls  = (int*)(Stab + 64);        // 2048
  int* cnt  = cls + NN;                 // 2048   } zeroed together (10240 ints)
  int* ncnt = cnt + NN;                 // 8192   }
  int* slot = ncnt + NN*NCLSS;          // NN*SLOT
  float* h1 = (float*)(slot + NN*SLOT); // 24576 (16B-aligned)
  float* A  = h1 + NN*HIDD;             // 24576
  float* B  = A + NN*HIDD;              // 24576

  float* outNL  = (float*)d_out;
  float4* outEL = (float4*)((float*)d_out + NN*NCLSS);

  // 1: tables + score table || zero cnt/ncnt + class extraction
  k_init<<<5, 512, 0, stream>>>(x, t, tW, tb,
                                Wq1,bq1, Wk1,bk1, Wv1,bv1, Ws1,bs1,
                                v1t, sk1t, Stab, cls, cnt);
  // 2: slot scatter + class histogram
  k_fill<<<EE/512, 512, 0, stream>>>(ei, cls, cnt, ncnt, slot);
  // 3: materialize h1 (layer-1 closed form, thread per node)
  k_h1<<<NN/512, 512, 0, stream>>>(cls, ncnt, v1t, sk1t, Stab, h1);
  // 4: u-factored layer-2 attention over h1 + logits/A/B
  k_attn2<<<NN/8, 512, 0, stream>>>(cnt, slot, h1,
                                    Wq2,bq2, Wk2,bk2, Wv2,bv2, Ws2,bs2,
                                    Wn,bn, We1,be1, A, B, outNL);
  // 5: dense pair MLP
  k_edge<<<dim3(32, 64), 256, 0, stream>>>(A, B, We2, be2, outEL);
}